// Round 17
// baseline (82.239 us; speedup 1.0000x reference)
//
#include <hip/hip_runtime.h>
#include <math.h>

#define FDIM  100
#define ODIM  180
#define HTOT  512
#define WTOT  512
#define TILE  32               // 32x32 pixel tile per (tile,slice) block
#define LDSW  49
#define NSLICE 8
#define SLICE_SZ 2250          // 18000/8 -> per-XCD-resident 2.6 MB slice
#define NTILE 256              // (512/32)^2
#define NBLK  (NTILE * NSLICE) // 2048 blocks  -- VERIFIED geometry for gid%8->XCD
#define TEMPERATURE 20.0f
#define THRESHOLD   55.0f

typedef float f32x4 __attribute__((ext_vector_type(4)));

// LESSONS (do not regress):
//  R12: slice->XCD locality ONLY verified at 256-thread / 2048-block geometry.
//  R13: odd-j rotation raised conflicts AND VALU cost.
//  R14: hipLaunchCooperativeKernel silently fails under graph capture here.
//  R10: explicit register rotate-pipelining regressed.
//  R9:  repack/alignment null — LDS issue count, not lines, is the cost.
//  R15: DPP butterfly WIN -> LDS pipe is issue-limited; cut DS instructions.
//  R16: vertical ds_read2_b32 pairing: (r,c)+(r+1,c) = uniform +49 dwords.

template <int CTRL>
__device__ __forceinline__ float dpp_ror_add(float v) {
    const int r = __builtin_amdgcn_mov_dpp(__float_as_int(v), CTRL, 0xf, 0xf, false);
    return v + __int_as_float(r);
}

// ws layout (bytes): [0, 16384) : float2 partial[2048] — all written every call
__global__ __launch_bounds__(256, 8) void filter_sliced(
    const float* __restrict__ x,
    const int*   __restrict__ freq,
    const int*   __restrict__ orient,
    const float* __restrict__ fb,
    float*       __restrict__ y,
    float2*      __restrict__ partial)
{
    __shared__ float tile[LDSW][LDSW];         // 49 x 49 floats = 9604 B (row 48 = pair partner for patch row 16)
    __shared__ int   sel[TILE * TILE];         // packed (idx<<10)|p, 4096 B
    __shared__ unsigned int nsel;

    const int gid   = blockIdx.x;
    const int slice = gid & (NSLICE - 1);
    const int t     = gid >> 3;                // tile id 0..255
    const int bx    = t & 15, by = t >> 4;
    const int tid   = threadIdx.x;
    const int lane  = tid & 63;

    if (tid == 0) nsel = 0;
    __syncthreads();

    // pass 1: per-pixel filter index + wave-aggregated compaction (1 atomic/wave/pass)
    const int lo = slice * SLICE_SZ;
    #pragma unroll
    for (int k = 0; k < 4; ++k) {
        const int p  = tid + k * 256;
        const int pr = p >> 5, pc = p & 31;
        const int pid = (by * TILE + pr) * WTOT + bx * TILE + pc;
        int f0 = freq[pid] - 1;
        int o0 = orient[pid] - 1;
        f0 = f0 < 0 ? 0 : (f0 > FDIM - 1 ? FDIM - 1 : f0);
        o0 = o0 < 0 ? 0 : (o0 > ODIM - 1 ? ODIM - 1 : o0);
        const int idx = f0 * ODIM + o0;
        const bool want = (idx >= lo && idx < lo + SLICE_SZ);
        const unsigned long long mask = __ballot(want);
        unsigned int base = 0;
        if (lane == 0) base = atomicAdd(&nsel, (unsigned int)__popcll(mask));
        base = __shfl(base, 0, 64);
        if (want) {
            const int pos = __popcll(mask & ((1ULL << lane) - 1ULL));
            sel[base + pos] = (idx << 10) | p;
        }
    }

    // stage 49x48 input region (zero-padded at image borders)
    const int h0 = by * TILE - 8;
    const int w0 = bx * TILE - 8;
    for (int i = tid; i < 49 * 48; i += 256) {
        const int r = i / 48, c = i - r * 48;
        const int gh = h0 + r, gw = w0 + c;
        float v = 0.f;
        if (gh >= 0 && gh < HTOT && gw >= 0 && gw < WTOT)
            v = x[gh * WTOT + gw];
        tile[r][c] = v;
    }
    __syncthreads();

    const unsigned int m = nsel;
    const int l  = tid & 15;                   // lane within quarter-wave
    const int qw = tid >> 4;                   // quarter-wave id 0..15

    // vertical pair table: pair p = 16j + l covers patch elements
    // e0 = 34*(p/17) + p%17  (row 2*(p/17), col p%17)  and  e1 = e0 + 17.
    // LDS offsets from the pixel base: rel = 2*(p/17)*49 + p%17, rel+49.
    // pk[j] = (rel << 9) | e0   (rel <= 800 -> 10 bits, e0 <= 288 -> 9 bits)
    int pk[10];
    #pragma unroll
    for (int j = 0; j < 10; ++j) {
        int p = 16 * j + l; if (p > 152) p = 152;
        const int q = p / 17, c = p - 17 * q;
        pk[j] = ((2 * q * LDSW + c) << 9) | (34 * q + c);
    }

    float mn = 3.4e38f, mx = -3.4e38f;

    for (unsigned int s = qw; s < m; s += 16) {
        const int packed = sel[s];
        const int tp  = packed & 1023;
        const int ppy = tp >> 5, ppx = tp & 31;
        const float* __restrict__ kf = fb + (size_t)(packed >> 10) * 289;
        const float* __restrict__ bp0 = &tile[ppy][ppx];

        float a0 = 0.f, a1 = 0.f, a2 = 0.f, a3 = 0.f;
        // j = 0..7: both pair elements unconditionally valid
        #pragma unroll
        for (int j = 0; j < 8; j += 2) {
            {
                const int pkj = pk[j];
                const float* bp = bp0 + (pkj >> 9);
                const int fe = pkj & 511;
                a0 = fmaf(kf[fe],      bp[0],    a0);
                a1 = fmaf(kf[fe + 17], bp[LDSW], a1);
            }
            {
                const int pkj = pk[j + 1];
                const float* bp = bp0 + (pkj >> 9);
                const int fe = pkj & 511;
                a2 = fmaf(kf[fe],      bp[0],    a2);
                a3 = fmaf(kf[fe + 17], bp[LDSW], a3);
            }
        }
        // j = 8: second element valid only for lanes l < 8
        {
            const int pkj = pk[8];
            const float* bp = bp0 + (pkj >> 9);
            const int fe = pkj & 511;
            a0 = fmaf(kf[fe], bp[0], a0);
            const float k1 = (l < 8) ? kf[fe + 17] : 0.f;
            a1 = fmaf(k1, bp[LDSW], a1);
        }
        // j = 9: single element, lanes l <= 8 only (l > 8 clamped dup x 0)
        {
            const int pkj = pk[9];
            const float* bp = bp0 + (pkj >> 9);
            const int fe = pkj & 511;
            const float k0 = (l <= 8) ? kf[fe] : 0.f;
            a2 = fmaf(k0, bp[0], a2);
        }
        float acc = (a0 + a1) + (a2 + a3);

        // 16-lane total via VALU DPP row-rotates (no LDS-pipe traffic)
        acc = dpp_ror_add<0x128>(acc);   // row_ror:8
        acc = dpp_ror_add<0x124>(acc);   // row_ror:4
        acc = dpp_ror_add<0x122>(acc);   // row_ror:2
        acc = dpp_ror_add<0x121>(acc);   // row_ror:1

        if (l == 0)
            y[(by * TILE + ppy) * WTOT + bx * TILE + ppx] = acc;
        mn = fminf(mn, acc);
        mx = fmaxf(mx, acc);
    }

    // ---- block min/max reduce, then ONE plain store to a unique slot ----
    #pragma unroll
    for (int off = 32; off > 0; off >>= 1) {
        mn = fminf(mn, __shfl_down(mn, off, 64));
        mx = fmaxf(mx, __shfl_down(mx, off, 64));
    }
    __shared__ float smn[4], smx[4];
    const int wid = tid >> 6;
    if (lane == 0) { smn[wid] = mn; smx[wid] = mx; }
    __syncthreads();
    if (tid == 0) {
        float bmn = smn[0], bmx = smx[0];
        #pragma unroll
        for (int i = 1; i < 4; ++i) {
            bmn = fminf(bmn, smn[i]);
            bmx = fmaxf(bmx, smx[i]);
        }
        partial[gid] = make_float2(bmn, bmx);
    }
}

// fused: re-reduce the 2048 partials (16 KB, L2-hit) + transform 4 px/thread
__global__ __launch_bounds__(256) void filter_final(
    float* __restrict__ y,
    const float2* __restrict__ partial)
{
    const int tid = threadIdx.x;
    float mn = 3.4e38f, mx = -3.4e38f;
    for (int i = tid; i < NBLK; i += 256) {
        const float2 p = partial[i];
        mn = fminf(mn, p.x);
        mx = fmaxf(mx, p.y);
    }
    #pragma unroll
    for (int off = 32; off > 0; off >>= 1) {
        mn = fminf(mn, __shfl_down(mn, off, 64));
        mx = fmaxf(mx, __shfl_down(mx, off, 64));
    }
    __shared__ float smn[4], smx[4];
    const int wid = tid >> 6, lane = tid & 63;
    if (lane == 0) { smn[wid] = mn; smx[wid] = mx; }
    __syncthreads();
    __shared__ float sfin[2];
    if (tid == 0) {
        float bmn = smn[0], bmx = smx[0];
        #pragma unroll
        for (int i = 1; i < 4; ++i) {
            bmn = fminf(bmn, smn[i]);
            bmx = fmaxf(bmx, smx[i]);
        }
        sfin[0] = bmn; sfin[1] = bmx;
    }
    __syncthreads();

    const float ymin = sfin[0];
    const float rng  = fmaxf(sfin[1] - ymin, 1e-8f);
    const float smin = 100.f / (1.f + expf( 11.f));   // 100*sigmoid(-11)
    const float smax = 100.f / (1.f + expf(-9.f));    // 100*sigmoid(+9)
    const float srng = fmaxf(smax - smin, 1e-8f);

    const int base = blockIdx.x * 1024 + tid * 4;
    f32x4 v = *reinterpret_cast<const f32x4*>(&y[base]);
    #pragma unroll
    for (int i = 0; i < 4; ++i) {
        const float o1 = 100.f * (v[i] - ymin) / rng;            // in [0,100]
        const float s  = 100.f / (1.f + expf(-(TEMPERATURE * (o1 * 0.01f - THRESHOLD * 0.01f))));
        v[i] = 100.f * (s - smin) / srng;
    }
    *reinterpret_cast<f32x4*>(&y[base]) = v;
}

extern "C" void kernel_launch(void* const* d_in, const int* in_sizes, int n_in,
                              void* d_out, int out_size, void* d_ws, size_t ws_size,
                              hipStream_t stream) {
    const float* x      = (const float*)d_in[0];
    const int*   freq   = (const int*)d_in[1];
    const int*   orient = (const int*)d_in[2];
    const float* fb     = (const float*)d_in[3];
    float*       out    = (float*)d_out;       // doubles as y scratch
    float2*      partial = (float2*)d_ws;      // 2048 per-block {min,max}

    // 256 tiles x 8 slices; consecutive gid = same tile across the 8 XCDs
    filter_sliced<<<dim3(NBLK), 256, 0, stream>>>(x, freq, orient, fb, out, partial);

    // 256 blocks x 256 threads x 4 px; each block inlines the partial-reduce
    filter_final<<<(HTOT * WTOT) / 1024, 256, 0, stream>>>(out, partial);
}

// Round 18
// 33.311 us; speedup vs baseline: 2.4688x; 2.4688x over previous
//
#include <hip/hip_runtime.h>
#include <math.h>

#define FDIM  100
#define ODIM  180
#define HTOT  512
#define WTOT  512
#define TILE  32               // 32x32 pixel tile per (tile,slice) block
#define REG   48               // staged region = TILE + 16
#define LDSW  49
#define NSLICE 8
#define SLICE_SZ 2250          // 18000/8 -> per-XCD-resident 2.6 MB slice
#define NTILE 256              // (512/32)^2
#define NBLK  (NTILE * NSLICE) // 2048 blocks
#define TEMPERATURE 20.0f
#define THRESHOLD   55.0f

typedef float f32x4 __attribute__((ext_vector_type(4)));

// LESSONS (do not regress):
//  R12/R17: slice->XCD locality requires resources to BIND at <=8 blocks/CU
//    (VGPR>=52 or LDS>17.8KB). VGPR-32 builds broke it (FETCH 24->181 MB).
//  R16: pairing must NOT scatter filter reads — keep 16-consecutive kf windows.
//  R15: DPP butterfly WIN — LDS pipe is issue-limited; cut DS instructions.
//  R14: hipLaunchCooperativeKernel silently fails under graph capture here.
//  R13: bank-rotation games null. R10: hand-pipelining null. R9: alignment null.

template <int CTRL>
__device__ __forceinline__ float dpp_ror_add(float v) {
    const int r = __builtin_amdgcn_mov_dpp(__float_as_int(v), CTRL, 0xf, 0xf, false);
    return v + __int_as_float(r);
}

// ws layout (bytes): [0, 16384) : float2 partial[2048] — all written every call
__global__ __launch_bounds__(256) void filter_sliced(
    const float* __restrict__ x,
    const int*   __restrict__ freq,
    const int*   __restrict__ orient,
    const float* __restrict__ fb,
    float*       __restrict__ y,
    float2*      __restrict__ partial)
{
    __shared__ float tile[REG][LDSW];          // 48 x 49 floats = 9408 B
    __shared__ int   sel[TILE * TILE];         // packed (idx<<10)|p, 4096 B
    __shared__ float occupancy_pad[1100];      // +4400 B -> LDS > 17.8 KB
                                               // forces <=8 blocks/CU (locality guard)
    __shared__ unsigned int nsel;

    const int gid   = blockIdx.x;
    const int slice = gid & (NSLICE - 1);
    const int t     = gid >> 3;                // tile id 0..255
    const int bx    = t & 15, by = t >> 4;
    const int tid   = threadIdx.x;
    const int lane  = tid & 63;

    if (tid == 0) nsel = 0;
    __syncthreads();

    // pass 1: per-pixel filter index + wave-aggregated compaction (1 atomic/wave/pass)
    const int lo = slice * SLICE_SZ;
    #pragma unroll
    for (int k = 0; k < 4; ++k) {
        const int p  = tid + k * 256;
        const int pr = p >> 5, pc = p & 31;
        const int pid = (by * TILE + pr) * WTOT + bx * TILE + pc;
        int f0 = freq[pid] - 1;
        int o0 = orient[pid] - 1;
        f0 = f0 < 0 ? 0 : (f0 > FDIM - 1 ? FDIM - 1 : f0);
        o0 = o0 < 0 ? 0 : (o0 > ODIM - 1 ? ODIM - 1 : o0);
        const int idx = f0 * ODIM + o0;
        const bool want = (idx >= lo && idx < lo + SLICE_SZ);
        const unsigned long long mask = __ballot(want);
        unsigned int base = 0;
        if (lane == 0) base = atomicAdd(&nsel, (unsigned int)__popcll(mask));
        base = __shfl(base, 0, 64);
        if (want) {
            const int pos = __popcll(mask & ((1ULL << lane) - 1ULL));
            sel[base + pos] = (idx << 10) | p;
        }
    }

    // stage 48x48 input region (zero-padded at image borders)
    const int h0 = by * TILE - 8;
    const int w0 = bx * TILE - 8;
    for (int i = tid; i < REG * REG; i += 256) {
        const int r = i / REG, c = i - r * REG;
        const int gh = h0 + r, gw = w0 + c;
        float v = 0.f;
        if (gh >= 0 && gh < HTOT && gw >= 0 && gw < WTOT)
            v = x[gh * WTOT + gw];
        tile[r][c] = v;
    }
    __syncthreads();

    const unsigned int m = nsel;
    const int l  = tid & 15;                   // lane within quarter-wave = patch COLUMN
    const int qw = tid >> 4;                   // quarter-wave id 0..15

    float mn = 3.4e38f, mx = -3.4e38f;

    // column-major mapping: lane l owns column l (rows 0..16) + column-16 row l.
    // Vertical pairs (r,l)+(r+1,l) are uniform +49 dwords -> ds_read2_b32;
    // filter reads kf[17r+l] stay 16-consecutive per row (coalesced).
    for (unsigned int s = qw; s < m; s += 16) {
        const int packed = sel[s];
        const int tp  = packed & 1023;
        const int ppy = tp >> 5, ppx = tp & 31;
        const float* __restrict__ kf = fb + (size_t)(packed >> 10) * 289;
        const float* __restrict__ bp = &tile[ppy][ppx];

        // filter: 17 coalesced row-loads + column-16 weights + e288
        float kv[17];
        #pragma unroll
        for (int r = 0; r < 17; ++r) kv[r] = kf[17 * r + l];
        const float kc   = kf[17 * l + 16];    // column-16 weight, row l
        const float k288 = kf[288];            // (16,16), used by lane 15 only

        float a0 = 0.f, a1 = 0.f, a2 = 0.f, a3 = 0.f;
        #pragma unroll
        for (int r = 0; r < 16; r += 2) {      // 8 x ds_read2_b32 (offsets 0,+49)
            const float p0 = bp[r * LDSW + l];
            const float p1 = bp[r * LDSW + LDSW + l];
            a0 = fmaf(kv[r],     p0, a0);
            a1 = fmaf(kv[r + 1], p1, a1);
        }
        a2 = fmaf(kv[16], bp[16 * LDSW + l], a2);          // row 16 single
        {                                                   // column 16: one read2
            const float q0 = bp[l * LDSW + 16];             // (l, 16)
            const float q1 = bp[l * LDSW + LDSW + 16];      // (l+1, 16)
            a2 = fmaf(kc, q0, a2);
            a3 = fmaf((l == 15) ? k288 : 0.f, q1, a3);      // lane15 -> e288
        }
        float acc = (a0 + a1) + (a2 + a3);

        // 16-lane total via VALU DPP row-rotates (no LDS-pipe traffic)
        acc = dpp_ror_add<0x128>(acc);   // row_ror:8
        acc = dpp_ror_add<0x124>(acc);   // row_ror:4
        acc = dpp_ror_add<0x122>(acc);   // row_ror:2
        acc = dpp_ror_add<0x121>(acc);   // row_ror:1

        if (l == 0)
            y[(by * TILE + ppy) * WTOT + bx * TILE + ppx] = acc;
        mn = fminf(mn, acc);
        mx = fmaxf(mx, acc);
    }

    // keep occupancy_pad alive (m <= 1024 always; compiler can't prove it)
    if (m > 1024u) tile[0][0] += occupancy_pad[tid];

    // ---- block min/max reduce, then ONE plain store to a unique slot ----
    #pragma unroll
    for (int off = 32; off > 0; off >>= 1) {
        mn = fminf(mn, __shfl_down(mn, off, 64));
        mx = fmaxf(mx, __shfl_down(mx, off, 64));
    }
    __shared__ float smn[4], smx[4];
    const int wid = tid >> 6;
    if (lane == 0) { smn[wid] = mn; smx[wid] = mx; }
    __syncthreads();
    if (tid == 0) {
        float bmn = smn[0], bmx = smx[0];
        #pragma unroll
        for (int i = 1; i < 4; ++i) {
            bmn = fminf(bmn, smn[i]);
            bmx = fmaxf(bmx, smx[i]);
        }
        partial[gid] = make_float2(bmn, bmx);
    }
}

// fused: re-reduce the 2048 partials (16 KB, L2-hit) + transform 4 px/thread
__global__ __launch_bounds__(256) void filter_final(
    float* __restrict__ y,
    const float2* __restrict__ partial)
{
    const int tid = threadIdx.x;
    float mn = 3.4e38f, mx = -3.4e38f;
    for (int i = tid; i < NBLK; i += 256) {
        const float2 p = partial[i];
        mn = fminf(mn, p.x);
        mx = fmaxf(mx, p.y);
    }
    #pragma unroll
    for (int off = 32; off > 0; off >>= 1) {
        mn = fminf(mn, __shfl_down(mn, off, 64));
        mx = fmaxf(mx, __shfl_down(mx, off, 64));
    }
    __shared__ float smn[4], smx[4];
    const int wid = tid >> 6, lane = tid & 63;
    if (lane == 0) { smn[wid] = mn; smx[wid] = mx; }
    __syncthreads();
    __shared__ float sfin[2];
    if (tid == 0) {
        float bmn = smn[0], bmx = smx[0];
        #pragma unroll
        for (int i = 1; i < 4; ++i) {
            bmn = fminf(bmn, smn[i]);
            bmx = fmaxf(bmx, smx[i]);
        }
        sfin[0] = bmn; sfin[1] = bmx;
    }
    __syncthreads();

    const float ymin = sfin[0];
    const float rng  = fmaxf(sfin[1] - ymin, 1e-8f);
    const float smin = 100.f / (1.f + expf( 11.f));   // 100*sigmoid(-11)
    const float smax = 100.f / (1.f + expf(-9.f));    // 100*sigmoid(+9)
    const float srng = fmaxf(smax - smin, 1e-8f);

    const int base = blockIdx.x * 1024 + tid * 4;
    f32x4 v = *reinterpret_cast<const f32x4*>(&y[base]);
    #pragma unroll
    for (int i = 0; i < 4; ++i) {
        const float o1 = 100.f * (v[i] - ymin) / rng;            // in [0,100]
        const float s  = 100.f / (1.f + expf(-(TEMPERATURE * (o1 * 0.01f - THRESHOLD * 0.01f))));
        v[i] = 100.f * (s - smin) / srng;
    }
    *reinterpret_cast<f32x4*>(&y[base]) = v;
}

extern "C" void kernel_launch(void* const* d_in, const int* in_sizes, int n_in,
                              void* d_out, int out_size, void* d_ws, size_t ws_size,
                              hipStream_t stream) {
    const float* x      = (const float*)d_in[0];
    const int*   freq   = (const int*)d_in[1];
    const int*   orient = (const int*)d_in[2];
    const float* fb     = (const float*)d_in[3];
    float*       out    = (float*)d_out;       // doubles as y scratch
    float2*      partial = (float2*)d_ws;      // 2048 per-block {min,max}

    // 256 tiles x 8 slices; consecutive gid = same tile across the 8 XCDs
    filter_sliced<<<dim3(NBLK), 256, 0, stream>>>(x, freq, orient, fb, out, partial);

    // 256 blocks x 256 threads x 4 px; each block inlines the partial-reduce
    filter_final<<<(HTOT * WTOT) / 1024, 256, 0, stream>>>(out, partial);
}

// Round 19
// 32.861 us; speedup vs baseline: 2.5027x; 1.0137x over previous
//
#include <hip/hip_runtime.h>
#include <math.h>

#define FDIM  100
#define ODIM  180
#define HTOT  512
#define WTOT  512
#define TILE  32               // 32x32 pixel tile per (tile,slice) block
#define REG   48               // staged region = TILE + 16
#define LDSW  49
#define NSLICE 8
#define SLICE_SZ 2250          // 18000/8 -> per-XCD-resident 2.6 MB slice
#define NTILE 256              // (512/32)^2
#define NBLK  (NTILE * NSLICE) // 2048 blocks  -- VERIFIED geometry for gid%8->XCD
#define TEMPERATURE 20.0f
#define THRESHOLD   55.0f

typedef float f32x4 __attribute__((ext_vector_type(4)));

// LESSONS (do not regress):
//  R12/R17: slice->XCD locality requires resources to BIND at <=8 blocks/CU
//    (VGPR 52 does it naturally here). Low-VGPR/high-occupancy builds broke it.
//  R16/R17: DS-instruction cuts (ds_read2 pairings) are NULL post-R15 — the
//    kernel is mixed issue/latency-bound, not LDS-pipe-bound anymore.
//  R15: DPP butterfly WIN (replaced 4 shfl-bpermutes with VALU rotates).
//  R14: hipLaunchCooperativeKernel silently fails under graph capture here.
//  R13: bank-rotation null. R10: hand-pipelining null. R9: alignment null.

template <int CTRL>
__device__ __forceinline__ float dpp_ror_add(float v) {
    const int r = __builtin_amdgcn_mov_dpp(__float_as_int(v), CTRL, 0xf, 0xf, false);
    return v + __int_as_float(r);
}

// ws layout (bytes): [0, 16384) : float2 partial[2048] — all written every call
__global__ __launch_bounds__(256) void filter_sliced(
    const float* __restrict__ x,
    const int*   __restrict__ freq,
    const int*   __restrict__ orient,
    const float* __restrict__ fb,
    float*       __restrict__ y,
    float2*      __restrict__ partial)
{
    __shared__ float tile[REG][LDSW];          // 48 x 49 floats = 9408 B
    __shared__ int   sel[TILE * TILE];         // packed (idx<<10)|p, 4096 B
    __shared__ unsigned int nsel;

    const int gid   = blockIdx.x;
    const int slice = gid & (NSLICE - 1);
    const int t     = gid >> 3;                // tile id 0..255
    const int bx    = t & 15, by = t >> 4;
    const int tid   = threadIdx.x;
    const int lane  = tid & 63;

    if (tid == 0) nsel = 0;
    __syncthreads();

    // pass 1: per-pixel filter index + wave-aggregated compaction (1 atomic/wave/pass)
    const int lo = slice * SLICE_SZ;
    #pragma unroll
    for (int k = 0; k < 4; ++k) {
        const int p  = tid + k * 256;
        const int pr = p >> 5, pc = p & 31;
        const int pid = (by * TILE + pr) * WTOT + bx * TILE + pc;
        int f0 = freq[pid] - 1;
        int o0 = orient[pid] - 1;
        f0 = f0 < 0 ? 0 : (f0 > FDIM - 1 ? FDIM - 1 : f0);
        o0 = o0 < 0 ? 0 : (o0 > ODIM - 1 ? ODIM - 1 : o0);
        const int idx = f0 * ODIM + o0;
        const bool want = (idx >= lo && idx < lo + SLICE_SZ);
        const unsigned long long mask = __ballot(want);
        unsigned int base = 0;
        if (lane == 0) base = atomicAdd(&nsel, (unsigned int)__popcll(mask));
        base = __shfl(base, 0, 64);
        if (want) {
            const int pos = __popcll(mask & ((1ULL << lane) - 1ULL));
            sel[base + pos] = (idx << 10) | p;
        }
    }

    // stage 48x48 input region (zero-padded at image borders)
    const int h0 = by * TILE - 8;
    const int w0 = bx * TILE - 8;
    for (int i = tid; i < REG * REG; i += 256) {
        const int r = i / REG, c = i - r * REG;
        const int gh = h0 + r, gw = w0 + c;
        float v = 0.f;
        if (gh >= 0 && gh < HTOT && gw >= 0 && gw < WTOT)
            v = x[gh * WTOT + gw];
        tile[r][c] = v;
    }
    __syncthreads();

    const unsigned int m = nsel;
    const int l  = tid & 15;                   // lane within quarter-wave
    const int qw = tid >> 4;                   // quarter-wave id 0..15

    int offs[18];
    #pragma unroll
    for (int j = 0; j < 18; ++j) {
        const int e = j * 16 + l;
        offs[j] = (e / 17) * LDSW + (e % 17);
    }

    float mn = 3.4e38f, mx = -3.4e38f;

    // each quarter-wave takes every 16th selected pixel (avg ~8 each);
    // batch the 19 filter loads, let the compiler schedule
    for (unsigned int s = qw; s < m; s += 16) {
        const int packed = sel[s];
        const int tp  = packed & 1023;
        const int ppy = tp >> 5, ppx = tp & 31;
        const float* __restrict__ kf = fb + (size_t)(packed >> 10) * 289;

        float kv[18];
        #pragma unroll
        for (int j = 0; j < 18; ++j) kv[j] = kf[j * 16 + l];
        const float kt = kf[288];

        const float* __restrict__ base = &tile[ppy][ppx];
        float a0 = 0.f, a1 = 0.f, a2 = 0.f, a3 = 0.f;
        #pragma unroll
        for (int j = 0; j < 16; j += 4) {
            a0 = fmaf(kv[j    ], base[offs[j    ]], a0);
            a1 = fmaf(kv[j + 1], base[offs[j + 1]], a1);
            a2 = fmaf(kv[j + 2], base[offs[j + 2]], a2);
            a3 = fmaf(kv[j + 3], base[offs[j + 3]], a3);
        }
        a0 = fmaf(kv[16], base[offs[16]], a0);
        a1 = fmaf(kv[17], base[offs[17]], a1);
        float acc = (a0 + a1) + (a2 + a3);
        if (l == 0) acc = fmaf(kt, base[16 * LDSW + 16], acc);  // e = 288 tail

        // 16-lane total via VALU DPP row-rotates (no LDS-pipe traffic)
        acc = dpp_ror_add<0x128>(acc);   // row_ror:8
        acc = dpp_ror_add<0x124>(acc);   // row_ror:4
        acc = dpp_ror_add<0x122>(acc);   // row_ror:2
        acc = dpp_ror_add<0x121>(acc);   // row_ror:1

        if (l == 0)
            y[(by * TILE + ppy) * WTOT + bx * TILE + ppx] = acc;
        mn = fminf(mn, acc);
        mx = fmaxf(mx, acc);
    }

    // ---- block min/max reduce, then ONE plain store to a unique slot ----
    #pragma unroll
    for (int off = 32; off > 0; off >>= 1) {
        mn = fminf(mn, __shfl_down(mn, off, 64));
        mx = fmaxf(mx, __shfl_down(mx, off, 64));
    }
    __shared__ float smn[4], smx[4];
    const int wid = tid >> 6;
    if (lane == 0) { smn[wid] = mn; smx[wid] = mx; }
    __syncthreads();
    if (tid == 0) {
        float bmn = smn[0], bmx = smx[0];
        #pragma unroll
        for (int i = 1; i < 4; ++i) {
            bmn = fminf(bmn, smn[i]);
            bmx = fmaxf(bmx, smx[i]);
        }
        partial[gid] = make_float2(bmn, bmx);
    }
}

// fused: re-reduce the 2048 partials (16 KB, L2-hit) + transform 4 px/thread
__global__ __launch_bounds__(256) void filter_final(
    float* __restrict__ y,
    const float2* __restrict__ partial)
{
    const int tid = threadIdx.x;
    float mn = 3.4e38f, mx = -3.4e38f;
    for (int i = tid; i < NBLK; i += 256) {
        const float2 p = partial[i];
        mn = fminf(mn, p.x);
        mx = fmaxf(mx, p.y);
    }
    #pragma unroll
    for (int off = 32; off > 0; off >>= 1) {
        mn = fminf(mn, __shfl_down(mn, off, 64));
        mx = fmaxf(mx, __shfl_down(mx, off, 64));
    }
    __shared__ float smn[4], smx[4];
    const int wid = tid >> 6, lane = tid & 63;
    if (lane == 0) { smn[wid] = mn; smx[wid] = mx; }
    __syncthreads();
    __shared__ float sfin[2];
    if (tid == 0) {
        float bmn = smn[0], bmx = smx[0];
        #pragma unroll
        for (int i = 1; i < 4; ++i) {
            bmn = fminf(bmn, smn[i]);
            bmx = fmaxf(bmx, smx[i]);
        }
        sfin[0] = bmn; sfin[1] = bmx;
    }
    __syncthreads();

    const float ymin = sfin[0];
    const float rng  = fmaxf(sfin[1] - ymin, 1e-8f);
    const float smin = 100.f / (1.f + expf( 11.f));   // 100*sigmoid(-11)
    const float smax = 100.f / (1.f + expf(-9.f));    // 100*sigmoid(+9)
    const float srng = fmaxf(smax - smin, 1e-8f);

    const int base = blockIdx.x * 1024 + tid * 4;
    f32x4 v = *reinterpret_cast<const f32x4*>(&y[base]);
    #pragma unroll
    for (int i = 0; i < 4; ++i) {
        const float o1 = 100.f * (v[i] - ymin) / rng;            // in [0,100]
        const float s  = 100.f / (1.f + expf(-(TEMPERATURE * (o1 * 0.01f - THRESHOLD * 0.01f))));
        v[i] = 100.f * (s - smin) / srng;
    }
    *reinterpret_cast<f32x4*>(&y[base]) = v;
}

extern "C" void kernel_launch(void* const* d_in, const int* in_sizes, int n_in,
                              void* d_out, int out_size, void* d_ws, size_t ws_size,
                              hipStream_t stream) {
    const float* x      = (const float*)d_in[0];
    const int*   freq   = (const int*)d_in[1];
    const int*   orient = (const int*)d_in[2];
    const float* fb     = (const float*)d_in[3];
    float*       out    = (float*)d_out;       // doubles as y scratch
    float2*      partial = (float2*)d_ws;      // 2048 per-block {min,max}

    // 256 tiles x 8 slices; consecutive gid = same tile across the 8 XCDs
    filter_sliced<<<dim3(NBLK), 256, 0, stream>>>(x, freq, orient, fb, out, partial);

    // 256 blocks x 256 threads x 4 px; each block inlines the partial-reduce
    filter_final<<<(HTOT * WTOT) / 1024, 256, 0, stream>>>(out, partial);
}